// Round 5
// baseline (209.252 us; speedup 1.0000x reference)
//
#include <hip/hip_runtime.h>

typedef __attribute__((ext_vector_type(2))) float f32x2;

namespace {
constexpr int kD  = 768;   // emb dim
constexpr int kM  = 96;    // subvectors
constexpr int kK  = 256;   // codes
constexpr int kDS = 8;     // dsub
constexpr int kThreads = 128;           // 2 waves
constexpr int kBPT = 8;                 // b rows per thread (4 packed pairs)
constexpr int kBPB = kThreads * kBPT;   // 1024 b per block
constexpr int kB   = 8192;
}

// numpy pairwise sum for n=8: ((q0+q1)+(q2+q3)) + ((q4+q5)+(q6+q7))
__device__ __forceinline__ float tree8_sq(float4 a, float4 b) {
    float q0 = __fmul_rn(a.x, a.x), q1 = __fmul_rn(a.y, a.y);
    float q2 = __fmul_rn(a.z, a.z), q3 = __fmul_rn(a.w, a.w);
    float q4 = __fmul_rn(b.x, b.x), q5 = __fmul_rn(b.y, b.y);
    float q6 = __fmul_rn(b.z, b.z), q7 = __fmul_rn(b.w, b.w);
    return __fadd_rn(__fadd_rn(__fadd_rn(q0, q1), __fadd_rn(q2, q3)),
                     __fadd_rn(__fadd_rn(q4, q5), __fadd_rn(q6, q7)));
}

__global__ __launch_bounds__(kThreads)
void pq_pk_kernel(const float* __restrict__ vecs,
                  const float* __restrict__ cbg,
                  float* __restrict__ out) {
    // fp semantics: no mul+add contraction anywhere in this function —
    // numpy does mul then add with separate roundings.
    #pragma clang fp contract(off)

    __shared__ float  s_c2[kK];        // exact f32 ||c||^2 (np tree8)
    __shared__ float4 s_cb[kK][2];     // raw code rows (for exact output copy)

    const int tid = threadIdx.x;
    const int m   = blockIdx.x % kM;
    const int bt  = blockIdx.x / kM;
    const float* __restrict__ cbm = cbg + (size_t)m * (kK * kDS);

    // ---- stage c2 + raw rows (coalesced: thread r reads 32B at 32B stride)
    for (int r = tid; r < kK; r += kThreads) {
        const float4* cr = reinterpret_cast<const float4*>(cbm + r * kDS);
        float4 c0 = cr[0], c1 = cr[1];
        s_cb[r][0] = c0; s_cb[r][1] = c1;
        s_c2[r] = tree8_sq(c0, c1);
    }
    __syncthreads();

    // ---- load kBPT v-rows, compute exact v2, store DOUBLED v pair-packed.
    // sum((2v)·c) is bitwise 2·sum(v·c): ×2 is a pure exponent shift, it
    // commutes with every IEEE rounding here (no over/underflow).
    const size_t b0 = (size_t)bt * kBPB + tid;
    f32x2 vv[kBPT / 2][kDS];   // [pair][elem] = {2*v_j0[e], 2*v_j1[e]}
    f32x2 v2p[kBPT / 2];
#pragma unroll
    for (int p = 0; p < kBPT / 2; ++p) {
#pragma unroll
        for (int h = 0; h < 2; ++h) {
            const int j = 2 * p + h;
            const float* vr = vecs + (b0 + (size_t)j * kThreads) * kD + m * kDS;
            float4 a = reinterpret_cast<const float4*>(vr)[0];
            float4 c = reinterpret_cast<const float4*>(vr)[1];
            v2p[p][h] = tree8_sq(a, c);      // from ORIGINAL v
            vv[p][0][h] = 2.0f * a.x; vv[p][1][h] = 2.0f * a.y;
            vv[p][2][h] = 2.0f * a.z; vv[p][3][h] = 2.0f * a.w;
            vv[p][4][h] = 2.0f * c.x; vv[p][5][h] = 2.0f * c.y;
            vv[p][6][h] = 2.0f * c.z; vv[p][7][h] = 2.0f * c.w;
        }
    }

    float best[kBPT];
    int   bestk[kBPT];
#pragma unroll
    for (int j = 0; j < kBPT; ++j) { best[j] = -3.402823466e38f; bestk[j] = 0; }

    // ---- main loop: codebook row via wave-uniform global reads (-> s_load),
    // c2 via uniform LDS broadcast; math in packed f32 pairs (v_pk_*_f32).
#pragma unroll 2
    for (int k = 0; k < kK; ++k) {
        const float* cr = cbm + k * kDS;
        const float c0 = cr[0], c1 = cr[1], c2 = cr[2], c3 = cr[3];
        const float c4 = cr[4], c5 = cr[5], c6 = cr[6], c7 = cr[7];
        const float n2 = s_c2[k];
#pragma unroll
        for (int p = 0; p < kBPT / 2; ++p) {
            // sequential mul-then-add chain per half == numpy einsum order
            f32x2 acc = vv[p][0] * c0;
            acc = acc + vv[p][1] * c1;
            acc = acc + vv[p][2] * c2;
            acc = acc + vv[p][3] * c3;
            acc = acc + vv[p][4] * c4;
            acc = acc + vv[p][5] * c5;
            acc = acc + vv[p][6] * c6;
            acc = acc + vv[p][7] * c7;
            // reference order: (2vc - v2) - c2, one rounding per step
            f32x2 pr = (acc - v2p[p]) - n2;
            // strict '>' ascending k == np.argmax first-index tie-break
            const int j0 = 2 * p, j1 = 2 * p + 1;
            { bool gt = pr[0] > best[j0];
              best[j0]  = gt ? pr[0] : best[j0];
              bestk[j0] = gt ? k : bestk[j0]; }
            { bool gt = pr[1] > best[j1];
              best[j1]  = gt ? pr[1] : best[j1];
              bestk[j1] = gt ? k : bestk[j1]; }
        }
    }

    // ---- output: exact copy of winning code row (bitwise == reference)
#pragma unroll
    for (int j = 0; j < kBPT; ++j) {
        const int kk = bestk[j];
        float4 q0 = s_cb[kk][0], q1 = s_cb[kk][1];
        float4* op = reinterpret_cast<float4*>(
            out + (b0 + (size_t)j * kThreads) * kD + m * kDS);
        op[0] = q0;
        op[1] = q1;
    }
}

extern "C" void kernel_launch(void* const* d_in, const int* in_sizes, int n_in,
                              void* d_out, int out_size, void* d_ws, size_t ws_size,
                              hipStream_t stream) {
    const float* vecs = (const float*)d_in[0];   // (8192, 768) f32
    const float* cbg  = (const float*)d_in[1];   // (96, 256, 8) f32
    float* out = (float*)d_out;                  // (8192, 768) f32

    dim3 grid(kM * (kB / kBPB));                 // 96 * 8 = 768 blocks
    pq_pk_kernel<<<grid, kThreads, 0, stream>>>(vecs, cbg, out);
}

// Round 7
// 152.473 us; speedup vs baseline: 1.3724x; 1.3724x over previous
//
#include <hip/hip_runtime.h>

typedef __attribute__((ext_vector_type(2))) float f32x2;

namespace {
constexpr int kB  = 8192;  // batch
constexpr int kD  = 768;   // emb dim
constexpr int kM  = 96;    // subvectors
constexpr int kK  = 256;   // codes
constexpr int kDS = 8;     // dsub
constexpr int kThreads = 256;           // 4 waves
constexpr int kBPT = 2;                 // b rows per thread (1 packed pair)
constexpr int kBT  = kThreads * kBPT;   // 512 b per block
}

// numpy pairwise sum for n=8: ((q0+q1)+(q2+q3)) + ((q4+q5)+(q6+q7))
__device__ __forceinline__ float tree8_sq(float4 a, float4 b) {
    float q0 = __fmul_rn(a.x, a.x), q1 = __fmul_rn(a.y, a.y);
    float q2 = __fmul_rn(a.z, a.z), q3 = __fmul_rn(a.w, a.w);
    float q4 = __fmul_rn(b.x, b.x), q5 = __fmul_rn(b.y, b.y);
    float q6 = __fmul_rn(b.z, b.z), q7 = __fmul_rn(b.w, b.w);
    return __fadd_rn(__fadd_rn(__fadd_rn(q0, q1), __fadd_rn(q2, q3)),
                     __fadd_rn(__fadd_rn(q4, q5), __fadd_rn(q6, q7)));
}

__global__ __launch_bounds__(kThreads)
void pq_pk2_kernel(const float* __restrict__ vecs,
                   const float* __restrict__ cbg,
                   float* __restrict__ out) {
    // numpy does mul then add with separate roundings — forbid FMA/pk_fma.
    #pragma clang fp contract(off)

    __shared__ float  s_c2[kK];        // exact f32 ||c||^2 (np tree8)
    __shared__ float4 s_cb[kK][2];     // raw f32 code rows

    const int tid = threadIdx.x;
    const int m   = blockIdx.x % kM;
    const int bt  = blockIdx.x / kM;

    // ---- stage codebook slice (thread t = code row t; fully coalesced)
    {
        const float4* src = reinterpret_cast<const float4*>(cbg) + (size_t)m * (kK * kDS / 4);
        float4 a = src[2 * tid + 0];
        float4 b = src[2 * tid + 1];
        s_cb[tid][0] = a; s_cb[tid][1] = b;
        s_c2[tid] = tree8_sq(a, b);
    }
    __syncthreads();

    // ---- load 2 v-rows; keep DOUBLED v packed {j0,j1} per element.
    // fl((2v)*c)=2*fl(v*c) and fl(2x+2y)=2*fl(x+y) (pure exponent shift,
    // no over/underflow here) => packed dot == bitwise 2*vc of numpy.
    const size_t b0 = (size_t)bt * kBT + tid;
    f32x2 vv[kDS];
    f32x2 v2;
#pragma unroll
    for (int h = 0; h < 2; ++h) {
        const float* vr = vecs + (b0 + (size_t)h * kThreads) * kD + m * kDS;
        float4 a = reinterpret_cast<const float4*>(vr)[0];
        float4 c = reinterpret_cast<const float4*>(vr)[1];
        v2[h] = tree8_sq(a, c);              // from ORIGINAL v (np tree8)
        vv[0][h] = 2.0f * a.x; vv[1][h] = 2.0f * a.y;
        vv[2][h] = 2.0f * a.z; vv[3][h] = 2.0f * a.w;
        vv[4][h] = 2.0f * c.x; vv[5][h] = 2.0f * c.y;
        vv[6][h] = 2.0f * c.z; vv[7][h] = 2.0f * c.w;
    }

    float best0 = -3.402823466e38f, best1 = -3.402823466e38f;
    int   bk0 = 0, bk1 = 0;

    // ---- argmax over 256 codes; codebook via LDS broadcast (wave-uniform),
    // math in packed f32 (v_pk_mul_f32 / v_pk_add_f32, IEEE per half).
#pragma unroll 4
    for (int k = 0; k < kK; ++k) {
        const float4 ca = s_cb[k][0];
        const float4 cb4 = s_cb[k][1];
        const float  n2 = s_c2[k];
        // sequential mul-then-add chain == numpy einsum rounding order
        f32x2 acc = vv[0] * ca.x;
        acc = acc + vv[1] * ca.y;
        acc = acc + vv[2] * ca.z;
        acc = acc + vv[3] * ca.w;
        acc = acc + vv[4] * cb4.x;
        acc = acc + vv[5] * cb4.y;
        acc = acc + vv[6] * cb4.z;
        acc = acc + vv[7] * cb4.w;
        // acc == fl(2*vc) bitwise; reference order: (2vc - v2) - c2
        f32x2 pr = (acc - v2) - n2;
        // strict '>' ascending k == np.argmax first-index tie-break
        { bool gt = pr[0] > best0; best0 = gt ? pr[0] : best0; bk0 = gt ? k : bk0; }
        { bool gt = pr[1] > best1; best1 = gt ? pr[1] : best1; bk1 = gt ? k : bk1; }
    }

    // ---- output: exact copy of winning code rows (bitwise == reference)
    {
        float4 q0 = s_cb[bk0][0], q1 = s_cb[bk0][1];
        float4* op = reinterpret_cast<float4*>(out + b0 * kD + m * kDS);
        op[0] = q0; op[1] = q1;
    }
    {
        float4 q0 = s_cb[bk1][0], q1 = s_cb[bk1][1];
        float4* op = reinterpret_cast<float4*>(out + (b0 + kThreads) * kD + m * kDS);
        op[0] = q0; op[1] = q1;
    }
}

extern "C" void kernel_launch(void* const* d_in, const int* in_sizes, int n_in,
                              void* d_out, int out_size, void* d_ws, size_t ws_size,
                              hipStream_t stream) {
    const float* vecs = (const float*)d_in[0];   // (8192, 768) f32
    const float* cbg  = (const float*)d_in[1];   // (96, 256, 8) f32
    float* out = (float*)d_out;                  // (8192, 768) f32

    dim3 grid(kM * (kB / kBT));                  // 96 * 16 = 1536 blocks
    pq_pk2_kernel<<<grid, kThreads, 0, stream>>>(vecs, cbg, out);
}